// Round 6
// baseline (506.080 us; speedup 1.0000x reference)
//
#include <hip/hip_runtime.h>
#include <hip/hip_fp16.h>

#define N_NODES 50000
#define N_EDGES 800000
#define D_IN    128
#define D_SH    16
#define D_OUT   128
#define N_PATHS 64

#define SEGN    128                      // nodes per segment (seg = dst>>7)
#define NSEG    391                      // ceil(50000/128)
#define NSEGP   512                      // padded for the 64-lane scan
#define CAPE    2560                     // entries/seg cap (mean 2048, sd 45)
#define EPB     3125                     // edges per bin block
#define BINB    256                      // bin blocks (256*3125 = 800000)
#define XCB     3125                     // xc blocks (16 nodes each)
#define BLK     256
#define BLK2    512                      // node kernel: 8 waves/block

// ---------------------------------------------------------------------------
// R14: edge-streaming node kernel with LDS fp32 accumulation. NO CSR.
// R13 post-mortem: persistent blocks regressed (57->97us) — 1564 units over
// 2048 blocks = <1 unit/block (stealing moot), 21KB LDS cut residency, the
// pop+barrier epoch serialized. Structural insight: per edge, the CSR build
// alone (2 LDS atomics + 2 LDS stores) costs more than direct accumulation
// (1 LDS atomic). Total useful compute is 153 MFLOP = ~1us; everything else
// is structure. So: delete the CSR.
//  * 391 blocks x 512 thr, acc[128][128] fp32 in LDS (64KB, 2 blocks/CU).
//  * wave g-strided over 64-edge groups: 1 coalesced meta load, readlane
//    broadcast; per edge 1x128B xc row + 1x32B sh16 row + 1 LDS atomicAdd
//    into acc[dl][ko_p]. 16 loads in flight per 8-edge sub-group.
//  * coeff folded into xc_h at build (h(coeff[p]*x[n][ki[p]])) — one less
//    mul/edge and one less rounding.
//  * epilogue: coalesced float4 acc->out dump (every valid row written).
// Bin kernel unchanged (R10-R13 proven); becomes the long pole next.
//
// Workspace:
//   segcnt @ 0          : 391*4 (memset 2048 covers)
//   meta   @ 2048       : 391*2560*4  =  4,003,840  (src | dl<<16)
//   sh16   @ 4,005,888  : 391*2560*32 = 32,030,720  (fp16 sh rows)
//   xc_h   @ 36,036,608 : 50000*64*2  =  6,400,000  (fp16 coeff*x table)
//   total 42,436,608  (< 57.8 MB harness workspace)
// ---------------------------------------------------------------------------
#define OFF_META 2048
#define OFF_SH16 (OFF_META + NSEG*CAPE*4)
#define OFF_XCH  (OFF_SH16 + NSEG*CAPE*32)

__global__ __launch_bounds__(BLK) void bin_kernel(
        const float* __restrict__ x, const int* __restrict__ ki,
        const float* __restrict__ coeff,
        const float* __restrict__ sh, const int* __restrict__ src,
        const int* __restrict__ dst, int* __restrict__ segcnt,
        int* __restrict__ meta, __half* __restrict__ sh16,
        __half* __restrict__ xc_h) {
    __shared__ int lcnt[NSEGP];
    __shared__ int lstart[NSEGP];
    __shared__ int lofs[NSEGP];
    __shared__ int gbase[NSEGP];
    __shared__ unsigned short sorted_[EPB];
    const int tid = threadIdx.x;

    if (blockIdx.x < BINB) {
        const int e0 = blockIdx.x * EPB;
        for (int s = tid; s < NSEGP; s += BLK) lcnt[s] = 0;
        __syncthreads();
        // pass 1: per-seg counts (coalesced dst read)
        for (int i = tid; i < EPB; i += BLK)
            atomicAdd(&lcnt[dst[e0 + i] >> 7], 1);
        __syncthreads();
        // wave0: exclusive prefix over 512 counters; waves 1-3: reserve
        // global ranges (one atomic per non-empty (block,seg))
        if (tid < 64) {
            int b8 = tid * 8, v[8], s0 = 0;
            #pragma unroll
            for (int k = 0; k < 8; ++k) { v[k] = lcnt[b8 + k]; s0 += v[k]; }
            int run = s0;
            #pragma unroll
            for (int off = 1; off < 64; off <<= 1) {
                int y = __shfl_up(run, off);
                if (tid >= off) run += y;
            }
            int acc = run - s0;
            #pragma unroll
            for (int k = 0; k < 8; ++k) {
                lstart[b8 + k] = acc; lofs[b8 + k] = acc; acc += v[k];
            }
        } else {
            for (int s = tid - 64; s < NSEG; s += BLK - 64) {
                int c = lcnt[s];
                gbase[s] = c ? atomicAdd(&segcnt[s], c) : 0;
            }
        }
        __syncthreads();
        // pass 2: scatter edge indices into seg-sorted LDS order
        for (int i = tid; i < EPB; i += BLK) {
            int r = atomicAdd(&lofs[dst[e0 + i] >> 7], 1);
            sorted_[r] = (unsigned short)i;
        }
        __syncthreads();
        // pass 3: emit in sorted order -> same-seg edges write contiguous
        // global runs (meta 4B, sh16 32B per edge, both append-sequential)
        for (int j = tid; j < EPB; j += BLK) {
            int i = sorted_[j];
            int e = e0 + i;
            int d = dst[e];
            int s = d >> 7;
            int pos = gbase[s] + (j - lstart[s]);
            if (pos < CAPE) {
                size_t gi = (size_t)s * CAPE + pos;
                meta[gi] = src[e] | ((d & 127) << 16);
                const float4* shv = (const float4*)(sh + (size_t)e * D_SH);
                float4 f0 = shv[0], f1 = shv[1], f2 = shv[2], f3 = shv[3];
                union { __half2 h[8]; int4 v[2]; } u;
                u.h[0] = __floats2half2_rn(f0.x, f0.y);
                u.h[1] = __floats2half2_rn(f0.z, f0.w);
                u.h[2] = __floats2half2_rn(f1.x, f1.y);
                u.h[3] = __floats2half2_rn(f1.z, f1.w);
                u.h[4] = __floats2half2_rn(f2.x, f2.y);
                u.h[5] = __floats2half2_rn(f2.z, f2.w);
                u.h[6] = __floats2half2_rn(f3.x, f3.y);
                u.h[7] = __floats2half2_rn(f3.z, f3.w);
                int4* dp = (int4*)(sh16 + gi * 16);
                dp[0] = u.v[0]; dp[1] = u.v[1];
            }
        }
    } else {
        // xc_h build: one wave -> 4 nodes; coeff FOLDED into the table
        const int b2   = blockIdx.x - BINB;
        const int lane = tid & 63;
        const int w    = tid >> 6;
        const int nb   = b2 * 16 + w * 4;               // covers [0,50000)
        const int kil  = ki[lane];
        const float cl = coeff[lane];
        float x0 = x[(size_t)(nb + 0) * D_IN + kil];
        float x1 = x[(size_t)(nb + 1) * D_IN + kil];
        float x2 = x[(size_t)(nb + 2) * D_IN + kil];
        float x3 = x[(size_t)(nb + 3) * D_IN + kil];
        xc_h[(size_t)(nb + 0) * N_PATHS + lane] = __float2half_rn(cl * x0);
        xc_h[(size_t)(nb + 1) * N_PATHS + lane] = __float2half_rn(cl * x1);
        xc_h[(size_t)(nb + 2) * N_PATHS + lane] = __float2half_rn(cl * x2);
        xc_h[(size_t)(nb + 3) * N_PATHS + lane] = __float2half_rn(cl * x3);
    }
}

__global__ __launch_bounds__(BLK2) void node_kernel(
        const int* __restrict__ segcnt, const int* __restrict__ meta,
        const __half* __restrict__ sh16, const __half* __restrict__ xc_h,
        const int* __restrict__ kj, const int* __restrict__ ko,
        float* __restrict__ out) {
    __shared__ float acc[SEGN][D_OUT];                  // 64 KB
    const int tid  = threadIdx.x;
    const int lane = tid & 63;
    const int w    = tid >> 6;
    const int seg  = blockIdx.x;
    const int n_e  = min(segcnt[seg], CAPE);
    const size_t mb = (size_t)seg * CAPE;
    const __half* shb = sh16 + mb * 16;

    const int kj_p = kj[lane];
    const int ko_p = ko[lane];

    // zero the accumulator (4096 float4 / 512 thr = 8 each)
    float4* accv = (float4*)&acc[0][0];
    #pragma unroll
    for (int i = 0; i < (SEGN * D_OUT / 4) / BLK2; ++i)
        accv[tid + i * BLK2] = make_float4(0.f, 0.f, 0.f, 0.f);
    __syncthreads();

    // main: waves stride over full 64-edge groups
    const int ngrp = n_e >> 6;
    for (int g = w; g < ngrp; g += BLK2 / 64) {
        const int jb = g << 6;
        const int mreg = meta[mb + jb + lane];          // coalesced 256B
        #pragma unroll
        for (int s8 = 0; s8 < 8; ++s8) {
            float xv[8], sv[8];
            int   dl[8];
            #pragma unroll
            for (int u = 0; u < 8; ++u) {
                int m = __builtin_amdgcn_readlane(mreg, s8 * 8 + u);
                int s = m & 0xFFFF;                     // SGPR (saddr loads)
                dl[u] = (m >> 16) & 127;
                xv[u] = __half2float(xc_h[(size_t)s * N_PATHS + lane]);
                sv[u] = __half2float(shb[(size_t)(jb + s8 * 8 + u) * 16 + kj_p]);
            }
            #pragma unroll
            for (int u = 0; u < 8; ++u)
                atomicAdd(&acc[dl[u]][ko_p], xv[u] * sv[u]);
        }
    }
    // tail (0..63 edges), round-robin over the 8 waves, pipelined
    const int jt  = ngrp << 6;
    const int rem = n_e - jt;
    if (rem > 0) {
        const int mreg = (jt + lane < n_e) ? meta[mb + jt + lane] : 0;
        float xv[8], sv[8];
        int   dl[8];
        #pragma unroll
        for (int t = 0; t < 8; ++t) {
            int u  = w + t * 8;
            bool go = u < rem;                          // wave-uniform
            int m  = __shfl(mreg, go ? u : 0);
            int s  = m & 0xFFFF;
            dl[t]  = (m >> 16) & 127;
            xv[t] = go ? __half2float(xc_h[(size_t)s * N_PATHS + lane]) : 0.f;
            sv[t] = go ? __half2float(shb[(size_t)(jt + u) * 16 + kj_p]) : 0.f;
        }
        #pragma unroll
        for (int t = 0; t < 8; ++t)
            if (w + t * 8 < rem)
                atomicAdd(&acc[dl[t]][ko_p], xv[t] * sv[t]);
    }
    __syncthreads();

    // epilogue: coalesced float4 dump; guard rows past N_NODES (last seg)
    float4* out4 = (float4*)(out + (size_t)seg * SEGN * D_OUT);
    const int rowbase = seg * SEGN;
    #pragma unroll
    for (int i = 0; i < (SEGN * D_OUT / 4) / BLK2; ++i) {
        int idx  = tid + i * BLK2;
        int node = rowbase + (idx >> 5);                // 32 float4 per row
        if (node < N_NODES) out4[idx] = accv[idx];
    }
}

extern "C" void kernel_launch(void* const* d_in, const int* in_sizes, int n_in,
                              void* d_out, int out_size, void* d_ws, size_t ws_size,
                              hipStream_t stream) {
    const float* x     = (const float*)d_in[0];
    const float* sh    = (const float*)d_in[1];
    const float* coeff = (const float*)d_in[2];
    const int*   src   = (const int*)d_in[3];
    const int*   dst   = (const int*)d_in[4];
    const int*   ki    = (const int*)d_in[5];
    const int*   kj    = (const int*)d_in[6];
    const int*   ko    = (const int*)d_in[7];
    float* out = (float*)d_out;

    char* p = (char*)d_ws;
    int*    segcnt = (int*)p;
    int*    meta   = (int*)(p + OFF_META);
    __half* sh16   = (__half*)(p + OFF_SH16);
    __half* xc_h   = (__half*)(p + OFF_XCH);
    (void)ws_size;   // need 42.4 MB; harness provides >= 57.8 MB

    hipMemsetAsync(p, 0, 2048, stream);   // segcnt
    bin_kernel<<<BINB + XCB, BLK, 0, stream>>>(
        x, ki, coeff, sh, src, dst, segcnt, meta, sh16, xc_h);
    node_kernel<<<NSEG, BLK2, 0, stream>>>(
        segcnt, meta, sh16, xc_h, kj, ko, out);
}

// Round 7
// 233.312 us; speedup vs baseline: 2.1691x; 2.1691x over previous
//
#include <hip/hip_runtime.h>
#include <hip/hip_fp16.h>

#define N_NODES 50000
#define N_EDGES 800000
#define D_IN    128
#define D_SH    16
#define D_OUT   128
#define N_PATHS 64

#define SEGN    128                      // nodes per segment (seg = dst>>7)
#define NSEG    391                      // ceil(50000/128)
#define NSEGP   512                      // padded for the 64-lane scan
#define CAPE    2560                     // entries/seg cap (mean 2048, sd 45)
#define EPB     6250                     // edges per bin block (R15: doubled)
#define BINB    128                      // bin blocks (128*6250 = 800000)
#define XCB     3125                     // xc blocks (16 nodes each)
#define BLK     256

#define QN      32                       // nodes per node-block (quarter-seg)
#define QCAP    1024                     // CSR cap (mean 512, sd 23)
#define NQB     (NSEG * 4)               // 1564 node blocks

// ---------------------------------------------------------------------------
// R15: revert node to R11 (proven 57us), attack bin's write drain.
// R14 post-mortem: per-EDGE LDS atomics are the one pipe no SQ counter
// shows — 800K scattered ds_add_f32 retired ~1-2 lanes/cy -> 354us.
// Lesson: accumulate in REGISTERS per node; at most 1 LDS chain per node.
// Bin theory: R10's build showed dur == WRITE_SIZE / 0.82 TB/s (57.5MB,
// 70us) -> scattered-write-drain bound, amplification 1.63x from short
// (8-edge) runs sharing 64B lines across producer blocks. Fix: 128 blocks
// x 6250 edges -> 16-edge runs (sh16 512B, meta 64B) -> amp ~1.1x.
// Also stage dst in LDS (ushort) to kill pass-2/3 global re-reads.
// Node kernel = R11 verbatim except gather unroll 8->16.
//
// Workspace:
//   segcnt @ 0          : 391*4 (memset 2048 covers)
//   meta   @ 2048       : 391*2560*4  =  4,003,840  (src | dl<<16)
//   sh16   @ 4,005,888  : 391*2560*32 = 32,030,720  (fp16 sh rows)
//   xc_h   @ 36,036,608 : 50000*64*2  =  6,400,000  (fp16 path-major table)
//   total 42,436,608  (< 57.8 MB harness workspace)
// ---------------------------------------------------------------------------
#define OFF_META 2048
#define OFF_SH16 (OFF_META + NSEG*CAPE*4)
#define OFF_XCH  (OFF_SH16 + NSEG*CAPE*32)

__global__ __launch_bounds__(BLK) void bin_kernel(
        const float* __restrict__ x, const int* __restrict__ ki,
        const float* __restrict__ sh, const int* __restrict__ src,
        const int* __restrict__ dst, int* __restrict__ segcnt,
        int* __restrict__ meta, __half* __restrict__ sh16,
        __half* __restrict__ xc_h) {
    __shared__ int lcnt[NSEGP];
    __shared__ int lstart[NSEGP];
    __shared__ int lofs[NSEGP];
    __shared__ int gbase[NSEGP];
    __shared__ unsigned short sorted_[EPB];
    __shared__ unsigned short dstsh[EPB];     // staged dst (node id < 65536)
    const int tid = threadIdx.x;

    if (blockIdx.x < BINB) {
        const int e0 = blockIdx.x * EPB;
        for (int s = tid; s < NSEGP; s += BLK) lcnt[s] = 0;
        __syncthreads();
        // pass 1: per-seg counts (coalesced dst read) + stage dst in LDS
        for (int i = tid; i < EPB; i += BLK) {
            int d = dst[e0 + i];
            dstsh[i] = (unsigned short)d;
            atomicAdd(&lcnt[d >> 7], 1);
        }
        __syncthreads();
        // wave0: exclusive prefix over 512 counters; waves 1-3: reserve
        // global ranges (one atomic per non-empty (block,seg))
        if (tid < 64) {
            int b8 = tid * 8, v[8], s0 = 0;
            #pragma unroll
            for (int k = 0; k < 8; ++k) { v[k] = lcnt[b8 + k]; s0 += v[k]; }
            int run = s0;
            #pragma unroll
            for (int off = 1; off < 64; off <<= 1) {
                int y = __shfl_up(run, off);
                if (tid >= off) run += y;
            }
            int acc = run - s0;
            #pragma unroll
            for (int k = 0; k < 8; ++k) {
                lstart[b8 + k] = acc; lofs[b8 + k] = acc; acc += v[k];
            }
        } else {
            for (int s = tid - 64; s < NSEG; s += BLK - 64) {
                int c = lcnt[s];
                gbase[s] = c ? atomicAdd(&segcnt[s], c) : 0;
            }
        }
        __syncthreads();
        // pass 2: scatter edge indices into seg-sorted LDS order (dst via LDS)
        for (int i = tid; i < EPB; i += BLK) {
            int r = atomicAdd(&lofs[dstsh[i] >> 7], 1);
            sorted_[r] = (unsigned short)i;
        }
        __syncthreads();
        // pass 3: emit in sorted order -> same-seg edges write contiguous
        // runs (~16 edges: meta 64B, sh16 512B -> near line-exclusive)
        for (int j = tid; j < EPB; j += BLK) {
            int i = sorted_[j];
            int e = e0 + i;
            int d = dstsh[i];
            int s = d >> 7;
            int pos = gbase[s] + (j - lstart[s]);
            if (pos < CAPE) {
                size_t gi = (size_t)s * CAPE + pos;
                meta[gi] = src[e] | ((d & 127) << 16);
                const float4* shv = (const float4*)(sh + (size_t)e * D_SH);
                float4 f0 = shv[0], f1 = shv[1], f2 = shv[2], f3 = shv[3];
                union { __half2 h[8]; int4 v[2]; } u;
                u.h[0] = __floats2half2_rn(f0.x, f0.y);
                u.h[1] = __floats2half2_rn(f0.z, f0.w);
                u.h[2] = __floats2half2_rn(f1.x, f1.y);
                u.h[3] = __floats2half2_rn(f1.z, f1.w);
                u.h[4] = __floats2half2_rn(f2.x, f2.y);
                u.h[5] = __floats2half2_rn(f2.z, f2.w);
                u.h[6] = __floats2half2_rn(f3.x, f3.y);
                u.h[7] = __floats2half2_rn(f3.z, f3.w);
                int4* dp = (int4*)(sh16 + gi * 16);
                dp[0] = u.v[0]; dp[1] = u.v[1];
            }
        }
    } else {
        // xc_h build: one wave -> 4 nodes
        const int b2   = blockIdx.x - BINB;
        const int lane = tid & 63;
        const int w    = tid >> 6;
        const int nb   = b2 * 16 + w * 4;               // covers [0,50000)
        const int kil  = ki[lane];
        float x0 = x[(size_t)(nb + 0) * D_IN + kil];
        float x1 = x[(size_t)(nb + 1) * D_IN + kil];
        float x2 = x[(size_t)(nb + 2) * D_IN + kil];
        float x3 = x[(size_t)(nb + 3) * D_IN + kil];
        xc_h[(size_t)(nb + 0) * N_PATHS + lane] = __float2half_rn(x0);
        xc_h[(size_t)(nb + 1) * N_PATHS + lane] = __float2half_rn(x1);
        xc_h[(size_t)(nb + 2) * N_PATHS + lane] = __float2half_rn(x2);
        xc_h[(size_t)(nb + 3) * N_PATHS + lane] = __float2half_rn(x3);
    }
}

__global__ __launch_bounds__(BLK) void node_kernel(
        const int* __restrict__ segcnt, const int* __restrict__ meta,
        const __half* __restrict__ sh16, const __half* __restrict__ xc_h,
        const float* __restrict__ coeff, const int* __restrict__ kj,
        const int* __restrict__ ko, float* __restrict__ out) {
    __shared__ int cnt_l[QN];
    __shared__ int nstart[QN + 1];
    __shared__ int ncur[QN];
    __shared__ unsigned short csr_src[QCAP];
    __shared__ unsigned short csr_idx[QCAP];
    __shared__ float srow[BLK / 64][D_OUT];
    const int tid  = threadIdx.x;
    const int lane = tid & 63;
    const int w    = tid >> 6;
    const int seg  = blockIdx.x >> 2;
    const int q    = blockIdx.x & 3;
    const int nb_l = q * QN;                 // local node base within segment
    const int n_e  = min(segcnt[seg], CAPE);
    const size_t mb = (size_t)seg * CAPE;
    const __half* shb = sh16 + mb * 16;

    if (tid < QN) cnt_l[tid] = 0;
    __syncthreads();
    // count pass: scan segment's meta stream, keep only this quarter's nodes
    for (int i = tid; i < n_e; i += BLK) {
        unsigned int u = (unsigned)(((meta[mb + i] >> 16) & 127) - nb_l);
        if (u < QN) atomicAdd(&cnt_l[u], 1);
    }
    __syncthreads();
    if (tid < QN) {                          // prefix over 32 counters
        int v = cnt_l[tid];
        int run = v;
        #pragma unroll
        for (int off = 1; off < QN; off <<= 1) {
            int y = __shfl_up(run, off);
            if (tid >= off) run += y;
        }
        nstart[tid] = run - v;
        ncur[tid]   = run - v;
        if (tid == QN - 1) nstart[QN] = run;
    }
    __syncthreads();
    // scatter pass: CSR carries (src, sh16-idx) as ushorts (src<65536 ok)
    for (int i = tid; i < n_e; i += BLK) {
        int m = meta[mb + i];
        unsigned int u = (unsigned)(((m >> 16) & 127) - nb_l);
        if (u < QN) {
            int r = atomicAdd(&ncur[u], 1);
            if (r < QCAP) {
                csr_src[r] = (unsigned short)(m & 0xFFFF);
                csr_idx[r] = (unsigned short)i;
            }
        }
    }
    __syncthreads();

    const int   kj_p = kj[lane];
    const int   ko_p = ko[lane];
    const float c_p  = coeff[lane];

    // wave w owns nodes c = w*8 .. w*8+7 (local), register accumulation
    #pragma unroll 1
    for (int k = 0; k < QN / (BLK / 64); ++k) {
        const int c    = w * (QN / (BLK / 64)) + k;
        const int node = seg * SEGN + nb_l + c;
        const int st   = min(nstart[c], QCAP);
        const int en   = min(nstart[c + 1], QCAP);
        float acc = 0.0f;
        int j = st;
        for (; j + 16 <= en; j += 16) {
            float xv[16], sv[16];
            #pragma unroll
            for (int u8 = 0; u8 < 16; ++u8) {
                int s = csr_src[j + u8];     // LDS broadcast (uniform addr)
                int i = csr_idx[j + u8];
                xv[u8] = __half2float(xc_h[(size_t)s * N_PATHS + lane]);
                sv[u8] = __half2float(shb[(size_t)i * 16 + kj_p]);
            }
            #pragma unroll
            for (int u8 = 0; u8 < 16; ++u8) acc += xv[u8] * sv[u8];
        }
        if (j < en) {                        // masked final group (1..15)
            float xv[16], sv[16];
            #pragma unroll
            for (int u8 = 0; u8 < 16; ++u8) {
                int jj = j + u8;
                int jc = jj < en ? jj : st;  // st valid (en > st here)
                int s = csr_src[jc];
                int i = csr_idx[jc];
                xv[u8] = __half2float(xc_h[(size_t)s * N_PATHS + lane]);
                sv[u8] = __half2float(shb[(size_t)i * 16 + kj_p]);
            }
            #pragma unroll
            for (int u8 = 0; u8 < 16; ++u8)
                if (j + u8 < en) acc += xv[u8] * sv[u8];
        }
        acc *= c_p;
        if (node < N_NODES) {
            // combine equal-ko lanes through the wave's PRIVATE LDS row.
            // per-wave DS ops are in-order -> no barriers (proven R8-R13)
            srow[w][lane]      = 0.0f;
            srow[w][lane + 64] = 0.0f;
            atomicAdd(&srow[w][ko_p], acc);
            float r0 = srow[w][lane];
            float r1 = srow[w][lane + 64];
            float* orow = out + (size_t)node * D_OUT;
            orow[lane]      = r0;
            orow[lane + 64] = r1;
        }
    }
}

extern "C" void kernel_launch(void* const* d_in, const int* in_sizes, int n_in,
                              void* d_out, int out_size, void* d_ws, size_t ws_size,
                              hipStream_t stream) {
    const float* x     = (const float*)d_in[0];
    const float* sh    = (const float*)d_in[1];
    const float* coeff = (const float*)d_in[2];
    const int*   src   = (const int*)d_in[3];
    const int*   dst   = (const int*)d_in[4];
    const int*   ki    = (const int*)d_in[5];
    const int*   kj    = (const int*)d_in[6];
    const int*   ko    = (const int*)d_in[7];
    float* out = (float*)d_out;

    char* p = (char*)d_ws;
    int*    segcnt = (int*)p;
    int*    meta   = (int*)(p + OFF_META);
    __half* sh16   = (__half*)(p + OFF_SH16);
    __half* xc_h   = (__half*)(p + OFF_XCH);
    (void)ws_size;   // need 42.4 MB; harness provides >= 57.8 MB

    hipMemsetAsync(p, 0, 2048, stream);   // segcnt
    bin_kernel<<<BINB + XCB, BLK, 0, stream>>>(
        x, ki, sh, src, dst, segcnt, meta, sh16, xc_h);
    node_kernel<<<NQB, BLK, 0, stream>>>(
        segcnt, meta, sh16, xc_h, coeff, kj, ko, out);
}

// Round 8
// 217.465 us; speedup vs baseline: 2.3272x; 1.0729x over previous
//
#include <hip/hip_runtime.h>
#include <hip/hip_fp16.h>

#define N_NODES 50000
#define N_EDGES 800000
#define D_IN    128
#define D_SH    16
#define D_OUT   128
#define N_PATHS 64

#define SEGN    128                      // nodes per segment (seg = dst>>7)
#define NSEG    391                      // ceil(50000/128)
#define NSEGP   512                      // padded for the 64-lane scan
#define CAPE    2560                     // entries/seg cap (mean 2048, sd 45)

#define EPB     2000                     // edges per scatter block
#define BINB    400                      // scatter blocks (400*2000 = 800000)
#define BLKA    512                      // scatter block threads (8 waves)
#define XCB     1563                     // xc blocks (32 nodes each, guarded)
#define BLK     256

#define QN      32                       // nodes per node-block (quarter-seg)
#define QCAP    1024                     // CSR cap (mean 512, sd 23)
#define NQB     (NSEG * 4)               // 1564 node blocks

// ---------------------------------------------------------------------------
// R16: bin TLP + dispatch split for attribution.
// R15 post-mortem: WRITE 57.5->35.9MB with dur 69->75us — scattered-write
// drain FALSIFIED as bin's bound. Occupancy 9%, VALU 2.2%, 1.2TB/s: the
// scatter blocks (128x4 waves) are latency-exposed in every barrier phase,
// plus an unexplained per-block cost that doesn't scale with iterations.
// This round: (1) scatter = 400 blocks x 512 thr (3.1x waves, 3.9
// iters/thread), short runs accepted (write amp proven non-binding);
// (2) src staged in LDS (pass 3's only scattered read left = sh payload);
// (3) xc build split into its OWN dispatch so rocprof reports scatter and
// xc separately — 3 rounds of bin guesswork ends here.
// Node kernel byte-identical to R15 (R11-lineage, proven ~57us).
//
// Workspace:
//   segcnt @ 0          : 391*4 (memset 2048 covers)
//   meta   @ 2048       : 391*2560*4  =  4,003,840  (src | dl<<16)
//   sh16   @ 4,005,888  : 391*2560*32 = 32,030,720  (fp16 sh rows)
//   xc_h   @ 36,036,608 : 50000*64*2  =  6,400,000  (fp16 path-major table)
//   total 42,436,608  (< 57.8 MB harness workspace)
// ---------------------------------------------------------------------------
#define OFF_META 2048
#define OFF_SH16 (OFF_META + NSEG*CAPE*4)
#define OFF_XCH  (OFF_SH16 + NSEG*CAPE*32)

__global__ __launch_bounds__(BLKA) void bin_scatter(
        const float* __restrict__ sh, const int* __restrict__ src,
        const int* __restrict__ dst, int* __restrict__ segcnt,
        int* __restrict__ meta, __half* __restrict__ sh16) {
    __shared__ int lcnt[NSEGP];
    __shared__ int lstart[NSEGP];
    __shared__ int lofs[NSEGP];
    __shared__ int gbase[NSEGP];
    __shared__ unsigned short sorted_[EPB];
    __shared__ unsigned short dstsh[EPB];   // node id < 65536 -> ushort ok
    __shared__ unsigned short srcsh[EPB];   // node id < 65536 -> ushort ok
    const int tid = threadIdx.x;
    const int e0  = blockIdx.x * EPB;

    lcnt[tid] = 0;                          // NSEGP == BLKA
    __syncthreads();
    // pass 1: coalesced src/dst read, stage in LDS, per-seg counts
    for (int i = tid; i < EPB; i += BLKA) {
        int d = dst[e0 + i];
        int s = src[e0 + i];
        dstsh[i] = (unsigned short)d;
        srcsh[i] = (unsigned short)s;
        atomicAdd(&lcnt[d >> 7], 1);
    }
    __syncthreads();
    // wave0: exclusive prefix over 512 counters; other waves: reserve
    // global ranges (one atomic per non-empty (block,seg))
    if (tid < 64) {
        int b8 = tid * 8, v[8], s0 = 0;
        #pragma unroll
        for (int k = 0; k < 8; ++k) { v[k] = lcnt[b8 + k]; s0 += v[k]; }
        int run = s0;
        #pragma unroll
        for (int off = 1; off < 64; off <<= 1) {
            int y = __shfl_up(run, off);
            if (tid >= off) run += y;
        }
        int acc = run - s0;
        #pragma unroll
        for (int k = 0; k < 8; ++k) {
            lstart[b8 + k] = acc; lofs[b8 + k] = acc; acc += v[k];
        }
    } else {
        for (int s = tid - 64; s < NSEG; s += BLKA - 64) {
            int c = lcnt[s];
            gbase[s] = c ? atomicAdd(&segcnt[s], c) : 0;
        }
    }
    __syncthreads();
    // pass 2: scatter edge indices into seg-sorted LDS order (LDS-only reads)
    for (int i = tid; i < EPB; i += BLKA) {
        int r = atomicAdd(&lofs[dstsh[i] >> 7], 1);
        sorted_[r] = (unsigned short)i;
    }
    __syncthreads();
    // pass 3: emit in sorted order; only scattered global read is the sh row
    for (int j = tid; j < EPB; j += BLKA) {
        int i = sorted_[j];
        int d = dstsh[i];
        int s = d >> 7;
        int pos = gbase[s] + (j - lstart[s]);
        if (pos < CAPE) {
            size_t gi = (size_t)s * CAPE + pos;
            meta[gi] = (int)srcsh[i] | ((d & 127) << 16);
            const float4* shv = (const float4*)(sh + (size_t)(e0 + i) * D_SH);
            float4 f0 = shv[0], f1 = shv[1], f2 = shv[2], f3 = shv[3];
            union { __half2 h[8]; int4 v[2]; } u;
            u.h[0] = __floats2half2_rn(f0.x, f0.y);
            u.h[1] = __floats2half2_rn(f0.z, f0.w);
            u.h[2] = __floats2half2_rn(f1.x, f1.y);
            u.h[3] = __floats2half2_rn(f1.z, f1.w);
            u.h[4] = __floats2half2_rn(f2.x, f2.y);
            u.h[5] = __floats2half2_rn(f2.z, f2.w);
            u.h[6] = __floats2half2_rn(f3.x, f3.y);
            u.h[7] = __floats2half2_rn(f3.z, f3.w);
            int4* dp = (int4*)(sh16 + gi * 16);
            dp[0] = u.v[0]; dp[1] = u.v[1];
        }
    }
}

__global__ __launch_bounds__(BLKA) void bin_xc(
        const float* __restrict__ x, const int* __restrict__ ki,
        __half* __restrict__ xc_h) {
    // one wave -> 4 nodes; 8 waves/block -> 32 nodes/block
    const int tid  = threadIdx.x;
    const int lane = tid & 63;
    const int w    = tid >> 6;
    const int nb   = blockIdx.x * 32 + w * 4;
    const int kil  = ki[lane];
    #pragma unroll
    for (int k = 0; k < 4; ++k) {
        int n = nb + k;
        if (n < N_NODES)
            xc_h[(size_t)n * N_PATHS + lane] =
                __float2half_rn(x[(size_t)n * D_IN + kil]);
    }
}

__global__ __launch_bounds__(BLK) void node_kernel(
        const int* __restrict__ segcnt, const int* __restrict__ meta,
        const __half* __restrict__ sh16, const __half* __restrict__ xc_h,
        const float* __restrict__ coeff, const int* __restrict__ kj,
        const int* __restrict__ ko, float* __restrict__ out) {
    __shared__ int cnt_l[QN];
    __shared__ int nstart[QN + 1];
    __shared__ int ncur[QN];
    __shared__ unsigned short csr_src[QCAP];
    __shared__ unsigned short csr_idx[QCAP];
    __shared__ float srow[BLK / 64][D_OUT];
    const int tid  = threadIdx.x;
    const int lane = tid & 63;
    const int w    = tid >> 6;
    const int seg  = blockIdx.x >> 2;
    const int q    = blockIdx.x & 3;
    const int nb_l = q * QN;                 // local node base within segment
    const int n_e  = min(segcnt[seg], CAPE);
    const size_t mb = (size_t)seg * CAPE;
    const __half* shb = sh16 + mb * 16;

    if (tid < QN) cnt_l[tid] = 0;
    __syncthreads();
    // count pass: scan segment's meta stream, keep only this quarter's nodes
    for (int i = tid; i < n_e; i += BLK) {
        unsigned int u = (unsigned)(((meta[mb + i] >> 16) & 127) - nb_l);
        if (u < QN) atomicAdd(&cnt_l[u], 1);
    }
    __syncthreads();
    if (tid < QN) {                          // prefix over 32 counters
        int v = cnt_l[tid];
        int run = v;
        #pragma unroll
        for (int off = 1; off < QN; off <<= 1) {
            int y = __shfl_up(run, off);
            if (tid >= off) run += y;
        }
        nstart[tid] = run - v;
        ncur[tid]   = run - v;
        if (tid == QN - 1) nstart[QN] = run;
    }
    __syncthreads();
    // scatter pass: CSR carries (src, sh16-idx) as ushorts (src<65536 ok)
    for (int i = tid; i < n_e; i += BLK) {
        int m = meta[mb + i];
        unsigned int u = (unsigned)(((m >> 16) & 127) - nb_l);
        if (u < QN) {
            int r = atomicAdd(&ncur[u], 1);
            if (r < QCAP) {
                csr_src[r] = (unsigned short)(m & 0xFFFF);
                csr_idx[r] = (unsigned short)i;
            }
        }
    }
    __syncthreads();

    const int   kj_p = kj[lane];
    const int   ko_p = ko[lane];
    const float c_p  = coeff[lane];

    // wave w owns nodes c = w*8 .. w*8+7 (local), register accumulation
    #pragma unroll 1
    for (int k = 0; k < QN / (BLK / 64); ++k) {
        const int c    = w * (QN / (BLK / 64)) + k;
        const int node = seg * SEGN + nb_l + c;
        const int st   = min(nstart[c], QCAP);
        const int en   = min(nstart[c + 1], QCAP);
        float acc = 0.0f;
        int j = st;
        for (; j + 16 <= en; j += 16) {
            float xv[16], sv[16];
            #pragma unroll
            for (int u8 = 0; u8 < 16; ++u8) {
                int s = csr_src[j + u8];     // LDS broadcast (uniform addr)
                int i = csr_idx[j + u8];
                xv[u8] = __half2float(xc_h[(size_t)s * N_PATHS + lane]);
                sv[u8] = __half2float(shb[(size_t)i * 16 + kj_p]);
            }
            #pragma unroll
            for (int u8 = 0; u8 < 16; ++u8) acc += xv[u8] * sv[u8];
        }
        if (j < en) {                        // masked final group (1..15)
            float xv[16], sv[16];
            #pragma unroll
            for (int u8 = 0; u8 < 16; ++u8) {
                int jj = j + u8;
                int jc = jj < en ? jj : st;  // st valid (en > st here)
                int s = csr_src[jc];
                int i = csr_idx[jc];
                xv[u8] = __half2float(xc_h[(size_t)s * N_PATHS + lane]);
                sv[u8] = __half2float(shb[(size_t)i * 16 + kj_p]);
            }
            #pragma unroll
            for (int u8 = 0; u8 < 16; ++u8)
                if (j + u8 < en) acc += xv[u8] * sv[u8];
        }
        acc *= c_p;
        if (node < N_NODES) {
            // combine equal-ko lanes through the wave's PRIVATE LDS row.
            // per-wave DS ops are in-order -> no barriers (proven R8-R15)
            srow[w][lane]      = 0.0f;
            srow[w][lane + 64] = 0.0f;
            atomicAdd(&srow[w][ko_p], acc);
            float r0 = srow[w][lane];
            float r1 = srow[w][lane + 64];
            float* orow = out + (size_t)node * D_OUT;
            orow[lane]      = r0;
            orow[lane + 64] = r1;
        }
    }
}

extern "C" void kernel_launch(void* const* d_in, const int* in_sizes, int n_in,
                              void* d_out, int out_size, void* d_ws, size_t ws_size,
                              hipStream_t stream) {
    const float* x     = (const float*)d_in[0];
    const float* sh    = (const float*)d_in[1];
    const float* coeff = (const float*)d_in[2];
    const int*   src   = (const int*)d_in[3];
    const int*   dst   = (const int*)d_in[4];
    const int*   ki    = (const int*)d_in[5];
    const int*   kj    = (const int*)d_in[6];
    const int*   ko    = (const int*)d_in[7];
    float* out = (float*)d_out;

    char* p = (char*)d_ws;
    int*    segcnt = (int*)p;
    int*    meta   = (int*)(p + OFF_META);
    __half* sh16   = (__half*)(p + OFF_SH16);
    __half* xc_h   = (__half*)(p + OFF_XCH);
    (void)ws_size;   // need 42.4 MB; harness provides >= 57.8 MB

    hipMemsetAsync(p, 0, 2048, stream);   // segcnt
    bin_xc<<<XCB, BLKA, 0, stream>>>(x, ki, xc_h);
    bin_scatter<<<BINB, BLKA, 0, stream>>>(
        sh, src, dst, segcnt, meta, sh16);
    node_kernel<<<NQB, BLK, 0, stream>>>(
        segcnt, meta, sh16, xc_h, coeff, kj, ko, out);
}

// Round 10
// 210.382 us; speedup vs baseline: 2.4055x; 1.0337x over previous
//
#include <hip/hip_runtime.h>
#include <hip/hip_fp16.h>

#define N_NODES 50000
#define N_EDGES 800000
#define D_IN    128
#define D_SH    16
#define D_OUT   128
#define N_PATHS 64

#define SEGN    128                      // nodes per segment (seg = dst>>7)
#define NSEG    391                      // ceil(50000/128)
#define NSEGP   512                      // padded for the 64-lane scan
#define CAPE    2560                     // entries/seg cap (mean 2048, sd 45)

#define EPB     2000                     // edges per scatter block
#define BINB    400                      // scatter blocks (400*2000 = 800000)
#define BLKA    512                      // scatter block threads (8 waves)
#define XCB     1563                     // xc blocks (32 nodes each, guarded)
#define BLK2    512                      // node kernel threads (8 waves)

#define QN      32                       // nodes per node-block (quarter-seg)
#define QCAP    1024                     // CSR cap (mean 512, sd 23)
#define NQB     (NSEG * 4)               // 1564 node blocks

// ---------------------------------------------------------------------------
// R17 resubmit (R9-round bench was an infra failure: "container failed
// twice" — no kernel signal; identical source resubmitted to preserve the
// clean A/B vs R16).
// R16 post-mortem: (a) attribution — scatter+xc both <64.6us, node is the
// long pole; (b) unroll 16 REGRESSED node 57.2->64.7 (R11 vs R16, only
// functional delta in that dispatch): half-empty masked tails (mean degree
// 16) waste ~8 loads/node and stretch the chain -> revert to 8.
// (c) occupancy 41%: grid 1564x256thr = 6.1 blocks/CU caps waves at
// ~24/CU averaged. Fix waves-per-block, not blocks: same 1564 blocks at
// 512 thr (8 waves) -> 48 waves/CU queued (saturates the 32 cap), scan
// iters/thread halve, each wave owns 4 nodes (was 8). R12's failure mode
// (redundant scan x2) is NOT repeated — scan work per segment unchanged.
// bin_scatter / bin_xc byte-identical to R16.
//
// Workspace:
//   segcnt @ 0          : 391*4 (memset 2048 covers)
//   meta   @ 2048       : 391*2560*4  =  4,003,840  (src | dl<<16)
//   sh16   @ 4,005,888  : 391*2560*32 = 32,030,720  (fp16 sh rows)
//   xc_h   @ 36,036,608 : 50000*64*2  =  6,400,000  (fp16 path-major table)
//   total 42,436,608  (< 57.8 MB harness workspace)
// ---------------------------------------------------------------------------
#define OFF_META 2048
#define OFF_SH16 (OFF_META + NSEG*CAPE*4)
#define OFF_XCH  (OFF_SH16 + NSEG*CAPE*32)

__global__ __launch_bounds__(BLKA) void bin_scatter(
        const float* __restrict__ sh, const int* __restrict__ src,
        const int* __restrict__ dst, int* __restrict__ segcnt,
        int* __restrict__ meta, __half* __restrict__ sh16) {
    __shared__ int lcnt[NSEGP];
    __shared__ int lstart[NSEGP];
    __shared__ int lofs[NSEGP];
    __shared__ int gbase[NSEGP];
    __shared__ unsigned short sorted_[EPB];
    __shared__ unsigned short dstsh[EPB];   // node id < 65536 -> ushort ok
    __shared__ unsigned short srcsh[EPB];   // node id < 65536 -> ushort ok
    const int tid = threadIdx.x;
    const int e0  = blockIdx.x * EPB;

    lcnt[tid] = 0;                          // NSEGP == BLKA
    __syncthreads();
    // pass 1: coalesced src/dst read, stage in LDS, per-seg counts
    for (int i = tid; i < EPB; i += BLKA) {
        int d = dst[e0 + i];
        int s = src[e0 + i];
        dstsh[i] = (unsigned short)d;
        srcsh[i] = (unsigned short)s;
        atomicAdd(&lcnt[d >> 7], 1);
    }
    __syncthreads();
    // wave0: exclusive prefix over 512 counters; other waves: reserve
    // global ranges (one atomic per non-empty (block,seg))
    if (tid < 64) {
        int b8 = tid * 8, v[8], s0 = 0;
        #pragma unroll
        for (int k = 0; k < 8; ++k) { v[k] = lcnt[b8 + k]; s0 += v[k]; }
        int run = s0;
        #pragma unroll
        for (int off = 1; off < 64; off <<= 1) {
            int y = __shfl_up(run, off);
            if (tid >= off) run += y;
        }
        int acc = run - s0;
        #pragma unroll
        for (int k = 0; k < 8; ++k) {
            lstart[b8 + k] = acc; lofs[b8 + k] = acc; acc += v[k];
        }
    } else {
        for (int s = tid - 64; s < NSEG; s += BLKA - 64) {
            int c = lcnt[s];
            gbase[s] = c ? atomicAdd(&segcnt[s], c) : 0;
        }
    }
    __syncthreads();
    // pass 2: scatter edge indices into seg-sorted LDS order (LDS-only reads)
    for (int i = tid; i < EPB; i += BLKA) {
        int r = atomicAdd(&lofs[dstsh[i] >> 7], 1);
        sorted_[r] = (unsigned short)i;
    }
    __syncthreads();
    // pass 3: emit in sorted order; only scattered global read is the sh row
    for (int j = tid; j < EPB; j += BLKA) {
        int i = sorted_[j];
        int d = dstsh[i];
        int s = d >> 7;
        int pos = gbase[s] + (j - lstart[s]);
        if (pos < CAPE) {
            size_t gi = (size_t)s * CAPE + pos;
            meta[gi] = (int)srcsh[i] | ((d & 127) << 16);
            const float4* shv = (const float4*)(sh + (size_t)(e0 + i) * D_SH);
            float4 f0 = shv[0], f1 = shv[1], f2 = shv[2], f3 = shv[3];
            union { __half2 h[8]; int4 v[2]; } u;
            u.h[0] = __floats2half2_rn(f0.x, f0.y);
            u.h[1] = __floats2half2_rn(f0.z, f0.w);
            u.h[2] = __floats2half2_rn(f1.x, f1.y);
            u.h[3] = __floats2half2_rn(f1.z, f1.w);
            u.h[4] = __floats2half2_rn(f2.x, f2.y);
            u.h[5] = __floats2half2_rn(f2.z, f2.w);
            u.h[6] = __floats2half2_rn(f3.x, f3.y);
            u.h[7] = __floats2half2_rn(f3.z, f3.w);
            int4* dp = (int4*)(sh16 + gi * 16);
            dp[0] = u.v[0]; dp[1] = u.v[1];
        }
    }
}

__global__ __launch_bounds__(BLKA) void bin_xc(
        const float* __restrict__ x, const int* __restrict__ ki,
        __half* __restrict__ xc_h) {
    // one wave -> 4 nodes; 8 waves/block -> 32 nodes/block
    const int tid  = threadIdx.x;
    const int lane = tid & 63;
    const int w    = tid >> 6;
    const int nb   = blockIdx.x * 32 + w * 4;
    const int kil  = ki[lane];
    #pragma unroll
    for (int k = 0; k < 4; ++k) {
        int n = nb + k;
        if (n < N_NODES)
            xc_h[(size_t)n * N_PATHS + lane] =
                __float2half_rn(x[(size_t)n * D_IN + kil]);
    }
}

__global__ __launch_bounds__(BLK2) void node_kernel(
        const int* __restrict__ segcnt, const int* __restrict__ meta,
        const __half* __restrict__ sh16, const __half* __restrict__ xc_h,
        const float* __restrict__ coeff, const int* __restrict__ kj,
        const int* __restrict__ ko, float* __restrict__ out) {
    __shared__ int cnt_l[QN];
    __shared__ int nstart[QN + 1];
    __shared__ int ncur[QN];
    __shared__ unsigned short csr_src[QCAP];
    __shared__ unsigned short csr_idx[QCAP];
    __shared__ float srow[BLK2 / 64][D_OUT];            // 4 KB
    const int tid  = threadIdx.x;
    const int lane = tid & 63;
    const int w    = tid >> 6;
    const int seg  = blockIdx.x >> 2;
    const int q    = blockIdx.x & 3;
    const int nb_l = q * QN;                 // local node base within segment
    const int n_e  = min(segcnt[seg], CAPE);
    const size_t mb = (size_t)seg * CAPE;
    const __half* shb = sh16 + mb * 16;

    if (tid < QN) cnt_l[tid] = 0;
    __syncthreads();
    // count pass: scan segment's meta stream, keep only this quarter's nodes
    for (int i = tid; i < n_e; i += BLK2) {
        unsigned int u = (unsigned)(((meta[mb + i] >> 16) & 127) - nb_l);
        if (u < QN) atomicAdd(&cnt_l[u], 1);
    }
    __syncthreads();
    if (tid < QN) {                          // prefix over 32 counters (wave 0)
        int v = cnt_l[tid];
        int run = v;
        #pragma unroll
        for (int off = 1; off < QN; off <<= 1) {
            int y = __shfl_up(run, off);
            if (tid >= off) run += y;
        }
        nstart[tid] = run - v;
        ncur[tid]   = run - v;
        if (tid == QN - 1) nstart[QN] = run;
    }
    __syncthreads();
    // scatter pass: CSR carries (src, sh16-idx) as ushorts (src<65536 ok)
    for (int i = tid; i < n_e; i += BLK2) {
        int m = meta[mb + i];
        unsigned int u = (unsigned)(((m >> 16) & 127) - nb_l);
        if (u < QN) {
            int r = atomicAdd(&ncur[u], 1);
            if (r < QCAP) {
                csr_src[r] = (unsigned short)(m & 0xFFFF);
                csr_idx[r] = (unsigned short)i;
            }
        }
    }
    __syncthreads();

    const int   kj_p = kj[lane];
    const int   ko_p = ko[lane];
    const float c_p  = coeff[lane];

    // wave w owns local nodes w*4 .. w*4+3, register accumulation
    #pragma unroll 1
    for (int k = 0; k < QN / (BLK2 / 64); ++k) {
        const int c    = w * (QN / (BLK2 / 64)) + k;
        const int node = seg * SEGN + nb_l + c;
        const int st   = min(nstart[c], QCAP);
        const int en   = min(nstart[c + 1], QCAP);
        float acc = 0.0f;
        int j = st;
        for (; j + 8 <= en; j += 8) {
            float xv[8], sv[8];
            #pragma unroll
            for (int u8 = 0; u8 < 8; ++u8) {
                int s = csr_src[j + u8];     // LDS broadcast (uniform addr)
                int i = csr_idx[j + u8];
                xv[u8] = __half2float(xc_h[(size_t)s * N_PATHS + lane]);
                sv[u8] = __half2float(shb[(size_t)i * 16 + kj_p]);
            }
            #pragma unroll
            for (int u8 = 0; u8 < 8; ++u8) acc += xv[u8] * sv[u8];
        }
        if (j < en) {                        // masked final group (1..7)
            float xv[8], sv[8];
            #pragma unroll
            for (int u8 = 0; u8 < 8; ++u8) {
                int jj = j + u8;
                int jc = jj < en ? jj : st;  // st valid (en > st here)
                int s = csr_src[jc];
                int i = csr_idx[jc];
                xv[u8] = __half2float(xc_h[(size_t)s * N_PATHS + lane]);
                sv[u8] = __half2float(shb[(size_t)i * 16 + kj_p]);
            }
            #pragma unroll
            for (int u8 = 0; u8 < 8; ++u8)
                if (j + u8 < en) acc += xv[u8] * sv[u8];
        }
        acc *= c_p;
        if (node < N_NODES) {
            // combine equal-ko lanes through the wave's PRIVATE LDS row.
            // per-wave DS ops are in-order -> no barriers (proven R8-R16)
            srow[w][lane]      = 0.0f;
            srow[w][lane + 64] = 0.0f;
            atomicAdd(&srow[w][ko_p], acc);
            float r0 = srow[w][lane];
            float r1 = srow[w][lane + 64];
            float* orow = out + (size_t)node * D_OUT;
            orow[lane]      = r0;
            orow[lane + 64] = r1;
        }
    }
}

extern "C" void kernel_launch(void* const* d_in, const int* in_sizes, int n_in,
                              void* d_out, int out_size, void* d_ws, size_t ws_size,
                              hipStream_t stream) {
    const float* x     = (const float*)d_in[0];
    const float* sh    = (const float*)d_in[1];
    const float* coeff = (const float*)d_in[2];
    const int*   src   = (const int*)d_in[3];
    const int*   dst   = (const int*)d_in[4];
    const int*   ki    = (const int*)d_in[5];
    const int*   kj    = (const int*)d_in[6];
    const int*   ko    = (const int*)d_in[7];
    float* out = (float*)d_out;

    char* p = (char*)d_ws;
    int*    segcnt = (int*)p;
    int*    meta   = (int*)(p + OFF_META);
    __half* sh16   = (__half*)(p + OFF_SH16);
    __half* xc_h   = (__half*)(p + OFF_XCH);
    (void)ws_size;   // need 42.4 MB; harness provides >= 57.8 MB

    hipMemsetAsync(p, 0, 2048, stream);   // segcnt
    bin_xc<<<XCB, BLKA, 0, stream>>>(x, ki, xc_h);
    bin_scatter<<<BINB, BLKA, 0, stream>>>(
        sh, src, dst, segcnt, meta, sh16);
    node_kernel<<<NQB, BLK2, 0, stream>>>(
        segcnt, meta, sh16, xc_h, coeff, kj, ko, out);
}